// Round 1
// baseline (137.879 us; speedup 1.0000x reference)
//
#include <hip/hip_runtime.h>
#include <hip/hip_bf16.h>

// Problem dims
#define BS   4096
#define DIN  784
#define DH   400
#define DZ   20

// Output layout (f32 elements)
#define OFF_RMU  0
#define OFF_RVAR 3211264          // 4096*784
#define OFF_MU   6422528          // 2*4096*784
#define OFF_LV   6504448          // OFF_MU + 4096*20
#define OFF_Z    6586368          // OFF_LV + 4096*20

// Workspace layout (bytes)
#define WS_H1_OFF  0              // f32 [4096][400]
#define WS_H3B_OFF 6553600        // bf16 [4096][416] (K padded to 416)

#define SQRT20F 4.47213595499958f

using short8 = __attribute__((ext_vector_type(8))) short;
using f4     = __attribute__((ext_vector_type(4))) float;

__device__ __forceinline__ short bf16r(float f) {
    union { float f; unsigned u; } v; v.f = f;
    unsigned r = (v.u + 0x7fffu + ((v.u >> 16) & 1u)) >> 16;
    return (short)r;
}

// ---------------------------------------------------------------------------
// K1: h1 = relu(x @ W1^T + b1)   [4096,400] = [4096,784] x [400,784]^T
// bf16 MFMA, K padded 784->800 (25 steps of 32). BM=128, BN=80.
// grid (5, 32), 256 threads (4 waves; wave w owns rows w*32..w*32+31).
// ---------------------------------------------------------------------------
__global__ __launch_bounds__(256, 2)
void k_gemm1(const float* __restrict__ x, const float* __restrict__ W1,
             const float* __restrict__ b1, float* __restrict__ h1) {
    __shared__ short la[128][40];   // 80B row stride -> conflict-free-ish b128
    __shared__ short lb[80][40];

    const int tid = threadIdx.x;
    const int w   = tid >> 6;
    const int l   = tid & 63;
    const int lg  = l >> 4, lr = l & 15;
    const int bn  = blockIdx.x;     // 0..4
    const int bm  = blockIdx.y;     // 0..31

    f4 acc[2][5];
#pragma unroll
    for (int i = 0; i < 2; ++i)
#pragma unroll
        for (int j = 0; j < 5; ++j) acc[i][j] = (f4){0.f, 0.f, 0.f, 0.f};

    for (int kt = 0; kt < 25; ++kt) {
        const int k0 = kt * 32;

        // stage A: 128x32 = 512 chunks of 8 bf16, 2 per thread
#pragma unroll
        for (int i = 0; i < 2; ++i) {
            int c = tid + i * 256;
            int row = c >> 2, cj = (c & 3) * 8;
            int gk = k0 + cj;
            const float* src = x + (size_t)(bm * 128 + row) * DIN + gk;
            short8 v;
            if (gk + 7 < DIN) {
                f4 f0 = *(const f4*)(src);
                f4 f1 = *(const f4*)(src + 4);
#pragma unroll
                for (int e = 0; e < 4; ++e) { v[e] = bf16r(f0[e]); v[4 + e] = bf16r(f1[e]); }
            } else {
#pragma unroll
                for (int e = 0; e < 8; ++e) v[e] = (gk + e < DIN) ? bf16r(src[e]) : (short)0;
            }
            *(short8*)&la[row][cj] = v;
        }
        // stage B: 80x32 = 320 chunks
        {
            auto stageB = [&](int c) {
                int row = c >> 2, cj = (c & 3) * 8;
                int gk = k0 + cj;
                const float* src = W1 + (size_t)(bn * 80 + row) * DIN + gk;
                short8 v;
                if (gk + 7 < DIN) {
                    f4 f0 = *(const f4*)(src);
                    f4 f1 = *(const f4*)(src + 4);
#pragma unroll
                    for (int e = 0; e < 4; ++e) { v[e] = bf16r(f0[e]); v[4 + e] = bf16r(f1[e]); }
                } else {
#pragma unroll
                    for (int e = 0; e < 8; ++e) v[e] = (gk + e < DIN) ? bf16r(src[e]) : (short)0;
                }
                *(short8*)&lb[row][cj] = v;
            };
            stageB(tid);
            if (tid < 64) stageB(tid + 256);
        }
        __syncthreads();

        short8 a0 = *(const short8*)&la[w * 32 + lr][lg * 8];
        short8 a1 = *(const short8*)&la[w * 32 + 16 + lr][lg * 8];
#pragma unroll
        for (int ni = 0; ni < 5; ++ni) {
            short8 b = *(const short8*)&lb[ni * 16 + lr][lg * 8];
            acc[0][ni] = __builtin_amdgcn_mfma_f32_16x16x32_bf16(a0, b, acc[0][ni], 0, 0, 0);
            acc[1][ni] = __builtin_amdgcn_mfma_f32_16x16x32_bf16(a1, b, acc[1][ni], 0, 0, 0);
        }
        __syncthreads();
    }

    // epilogue: bias + relu, f32 store
#pragma unroll
    for (int mi = 0; mi < 2; ++mi)
#pragma unroll
        for (int ni = 0; ni < 5; ++ni) {
            int col = bn * 80 + ni * 16 + lr;
            float bias = b1[col];
#pragma unroll
            for (int r = 0; r < 4; ++r) {
                int row = bm * 128 + w * 32 + mi * 16 + lg * 4 + r;
                float v = acc[mi][ni][r] + bias;
                h1[(size_t)row * DH + col] = v > 0.f ? v : 0.f;
            }
        }
}

// ---------------------------------------------------------------------------
// K2: mu/logvar = h1 @ W21^T/W22^T + b   (fp32 vector, one thread per (b,i))
// grid 640 x 256 = 4096*40 threads
// ---------------------------------------------------------------------------
__global__ void k_mulv(const float* __restrict__ h1, const float* __restrict__ W21,
                       const float* __restrict__ b21, const float* __restrict__ W22,
                       const float* __restrict__ b22, float* __restrict__ out) {
    int gid = blockIdx.x * 256 + threadIdx.x;
    int b = gid / 40;
    int i = gid - b * 40;
    bool is_mu = i < 20;
    int ii = is_mu ? i : i - 20;
    const float* wrow = (is_mu ? W21 : W22) + ii * DH;
    const float* hrow = h1 + (size_t)b * DH;
    float acc = 0.f;
#pragma unroll 4
    for (int k = 0; k < DH; k += 4) {
        f4 hv = *(const f4*)(hrow + k);
        f4 wv = *(const f4*)(wrow + k);
        acc += hv[0] * wv[0] + hv[1] * wv[1] + hv[2] * wv[2] + hv[3] * wv[3];
    }
    acc += is_mu ? b21[ii] : b22[ii];
    out[(is_mu ? OFF_MU : OFF_LV) + b * 20 + ii] = acc;
}

// ---------------------------------------------------------------------------
// K3: z[s][b][j] = mu[b][j] +/- sqrt(20)*logvar[b][sp]*(j==sp)
// grid 12800 x 256 = 40*4096*20 threads (reads+writes d_out; disjoint regions)
// ---------------------------------------------------------------------------
__global__ void k_z(float* out) {
    unsigned gid = blockIdx.x * 256u + threadIdx.x;
    unsigned s = gid / 81920u;
    unsigned rem = gid - s * 81920u;
    unsigned b = rem / 20u;
    unsigned j = rem - b * 20u;
    unsigned sp = s < 20u ? s : s - 20u;
    float sign = s < 20u ? 1.f : -1.f;
    float v = out[OFF_MU + b * 20u + j];
    if (j == sp) v += sign * SQRT20F * out[OFF_LV + b * 20u + j];
    out[OFF_Z + gid] = v;
}

// ---------------------------------------------------------------------------
// K4: h3 = relu(z_last @ W3^T + b3), written as bf16 [4096][416] (zero-padded)
// z_last[b][j] = mu[b][j] - (j==19)*sqrt(20)*logvar[b][19]
// grid 6656 x 256 = 4096*416 threads
// ---------------------------------------------------------------------------
__global__ void k_h3(const float* out_ro, const float* __restrict__ W3,
                     const float* __restrict__ b3, short* __restrict__ h3b) {
    int gid = blockIdx.x * 256 + threadIdx.x;
    int b = gid / 416;
    int n = gid - b * 416;
    if (n >= DH) { h3b[gid] = 0; return; }
    const float* mu = out_ro + OFF_MU + (size_t)b * 20;
    float lv19 = out_ro[OFF_LV + (size_t)b * 20 + 19];
    const float* wrow = W3 + n * DZ;
    float acc = b3[n];
#pragma unroll
    for (int j = 0; j < DZ; ++j) acc += mu[j] * wrow[j];
    acc -= SQRT20F * lv19 * wrow[19];
    acc = acc > 0.f ? acc : 0.f;
    h3b[gid] = bf16r(acc);
}

// ---------------------------------------------------------------------------
// K5: recon_mu = h3 @ W41^T + b41 ; recon_var = h3 @ W42^T + b42
// [4096,784] = [4096,400(pad 416)] x [784,400]^T, dual-B bf16 MFMA
// BM=128, BN=112, 13 K-steps of 32. grid (7, 32), 256 threads.
// ---------------------------------------------------------------------------
__global__ __launch_bounds__(256, 2)
void k_gemm4(const short* __restrict__ h3b, const float* __restrict__ W41,
             const float* __restrict__ W42, const float* __restrict__ b41,
             const float* __restrict__ b42, float* __restrict__ out) {
    __shared__ short la[128][40];
    __shared__ short lb1[112][40];
    __shared__ short lb2[112][40];

    const int tid = threadIdx.x;
    const int w   = tid >> 6;
    const int l   = tid & 63;
    const int lg  = l >> 4, lr = l & 15;
    const int bn  = blockIdx.x;     // 0..6
    const int bm  = blockIdx.y;     // 0..31

    f4 acc[2][7][2];
#pragma unroll
    for (int i = 0; i < 2; ++i)
#pragma unroll
        for (int j = 0; j < 7; ++j)
#pragma unroll
            for (int q = 0; q < 2; ++q) acc[i][j][q] = (f4){0.f, 0.f, 0.f, 0.f};

    for (int kt = 0; kt < 13; ++kt) {
        const int k0 = kt * 32;

        // stage A (bf16 direct): 128x32 = 512 chunks
#pragma unroll
        for (int i = 0; i < 2; ++i) {
            int c = tid + i * 256;
            int row = c >> 2, cj = (c & 3) * 8;
            *(short8*)&la[row][cj] =
                *(const short8*)(h3b + (size_t)(bm * 128 + row) * 416 + k0 + cj);
        }
        // stage B1/B2 (f32 -> bf16): 112x32 = 448 chunks each
        auto stageW = [&](short (*lds)[40], const float* W, int c) {
            int row = c >> 2, cj = (c & 3) * 8;
            int gk = k0 + cj;
            const float* src = W + (size_t)(bn * 112 + row) * DH + gk;
            short8 v;
            if (gk + 7 < DH) {
                f4 f0 = *(const f4*)(src);
                f4 f1 = *(const f4*)(src + 4);
#pragma unroll
                for (int e = 0; e < 4; ++e) { v[e] = bf16r(f0[e]); v[4 + e] = bf16r(f1[e]); }
            } else {
#pragma unroll
                for (int e = 0; e < 8; ++e) v[e] = (gk + e < DH) ? bf16r(src[e]) : (short)0;
            }
            *(short8*)&lds[row][cj] = v;
        };
        stageW(lb1, W41, tid);
        if (tid < 192) stageW(lb1, W41, tid + 256);
        stageW(lb2, W42, tid);
        if (tid < 192) stageW(lb2, W42, tid + 256);
        __syncthreads();

        short8 a0 = *(const short8*)&la[w * 32 + lr][lg * 8];
        short8 a1 = *(const short8*)&la[w * 32 + 16 + lr][lg * 8];
#pragma unroll
        for (int ni = 0; ni < 7; ++ni) {
            short8 bA = *(const short8*)&lb1[ni * 16 + lr][lg * 8];
            short8 bB = *(const short8*)&lb2[ni * 16 + lr][lg * 8];
            acc[0][ni][0] = __builtin_amdgcn_mfma_f32_16x16x32_bf16(a0, bA, acc[0][ni][0], 0, 0, 0);
            acc[1][ni][0] = __builtin_amdgcn_mfma_f32_16x16x32_bf16(a1, bA, acc[1][ni][0], 0, 0, 0);
            acc[0][ni][1] = __builtin_amdgcn_mfma_f32_16x16x32_bf16(a0, bB, acc[0][ni][1], 0, 0, 0);
            acc[1][ni][1] = __builtin_amdgcn_mfma_f32_16x16x32_bf16(a1, bB, acc[1][ni][1], 0, 0, 0);
        }
        __syncthreads();
    }

    // epilogue
#pragma unroll
    for (int mi = 0; mi < 2; ++mi)
#pragma unroll
        for (int ni = 0; ni < 7; ++ni) {
            int col = bn * 112 + ni * 16 + lr;
            float bias1 = b41[col];
            float bias2 = b42[col];
#pragma unroll
            for (int r = 0; r < 4; ++r) {
                size_t row = (size_t)(bm * 128 + w * 32 + mi * 16 + lg * 4 + r);
                out[OFF_RMU  + row * DIN + col] = acc[mi][ni][0][r] + bias1;
                out[OFF_RVAR + row * DIN + col] = acc[mi][ni][1][r] + bias2;
            }
        }
}

// ---------------------------------------------------------------------------
extern "C" void kernel_launch(void* const* d_in, const int* in_sizes, int n_in,
                              void* d_out, int out_size, void* d_ws, size_t ws_size,
                              hipStream_t stream) {
    const float* x   = (const float*)d_in[0];
    const float* W1  = (const float*)d_in[1];
    const float* b1  = (const float*)d_in[2];
    const float* W21 = (const float*)d_in[3];
    const float* b21 = (const float*)d_in[4];
    const float* W22 = (const float*)d_in[5];
    const float* b22 = (const float*)d_in[6];
    const float* W3  = (const float*)d_in[7];
    const float* b3  = (const float*)d_in[8];
    const float* W41 = (const float*)d_in[9];
    const float* b41 = (const float*)d_in[10];
    const float* W42 = (const float*)d_in[11];
    const float* b42 = (const float*)d_in[12];

    float* out = (float*)d_out;
    float* h1  = (float*)((char*)d_ws + WS_H1_OFF);
    short* h3b = (short*)((char*)d_ws + WS_H3B_OFF);

    k_gemm1<<<dim3(5, 32), 256, 0, stream>>>(x, W1, b1, h1);
    k_mulv<<<640, 256, 0, stream>>>(h1, W21, b21, W22, b22, out);
    k_z<<<12800, 256, 0, stream>>>(out);
    k_h3<<<6656, 256, 0, stream>>>(out, W3, b3, h3b);
    k_gemm4<<<dim3(7, 32), 256, 0, stream>>>(h3b, W41, W42, b41, b42, out);
}

// Round 2
// 69.189 us; speedup vs baseline: 1.9928x; 1.9928x over previous
//
#include <hip/hip_runtime.h>
#include <hip/hip_bf16.h>

// Problem dims
#define BS   4096
#define DIN  784
#define DH   400
#define DZ   20

// K paddings
#define KP1  832    // W1b cols (gemm1 K: 784 -> 832 = 13*64)
#define KPH  416    // h1b / W2cat cols (400 -> 416 = 13*32)
#define KPD  448    // h3b / W41b / W42b cols (400 -> 448 = 14*32)

// Output layout (f32 elements)
#define OFF_RMU  0
#define OFF_RVAR 3211264
#define OFF_MU   6422528
#define OFF_LV   6504448
#define OFF_Z    6586368

// Workspace layout (bytes)
#define WS_W1B   0          // bf16 [400][832]   = 665600
#define WS_W41B  665600     // bf16 [784][448]   = 702464
#define WS_W42B  1368064    // bf16 [784][448]   = 702464
#define WS_W2C   2070528    // bf16 [48][416]    = 39936
#define WS_H1B   2110464    // bf16 [4096][416]  = 3407872
#define WS_H3B   5518336    // bf16 [4096][448]  = 3670016
// total 9188352 bytes

#define SQRT20F 4.47213595499958f

using short8 = __attribute__((ext_vector_type(8))) short;
using f4     = __attribute__((ext_vector_type(4))) float;

__device__ __forceinline__ short bf16r(float f) {
    union { float f; unsigned u; } v; v.f = f;
    unsigned r = (v.u + 0x7fffu + ((v.u >> 16) & 1u)) >> 16;
    return (short)r;
}

__device__ __forceinline__ void glds16(const void* g, void* l) {
    __builtin_amdgcn_global_load_lds(
        (const __attribute__((address_space(1))) unsigned int*)g,
        (__attribute__((address_space(3))) unsigned int*)l,
        16, 0, 0);
}

// ---------------------------------------------------------------------------
// k_cvt: pre-convert all weights to bf16 with zero K-padding.
// chunk = 16B = 8 bf16. Regions: W1b, W41b, W42b, W2cat.
// ---------------------------------------------------------------------------
__global__ void k_cvt(const float* __restrict__ W1, const float* __restrict__ W41,
                      const float* __restrict__ W42, const float* __restrict__ W21,
                      const float* __restrict__ W22, char* __restrict__ ws) {
    const int N0 = 400 * 104;                 // W1b
    const int N1 = N0 + 784 * 56;             // W41b
    const int N2 = N1 + 784 * 56;             // W42b
    const int N3 = N2 + 48 * 52;              // W2cat
    int gid = blockIdx.x * 256 + threadIdx.x;
    if (gid >= N3) return;

    int p, CH, DC, Ksrc;
    const float* s;
    short* d;
    if (gid < N0)      { p = gid;      CH = 104; DC = 98; s = W1;  d = (short*)(ws + WS_W1B);  Ksrc = 784; }
    else if (gid < N1) { p = gid - N0; CH = 56;  DC = 50; s = W41; d = (short*)(ws + WS_W41B); Ksrc = 400; }
    else if (gid < N2) { p = gid - N1; CH = 56;  DC = 50; s = W42; d = (short*)(ws + WS_W42B); Ksrc = 400; }
    else               { p = gid - N2; CH = 52;  DC = 50; s = nullptr; d = (short*)(ws + WS_W2C); Ksrc = 400; }

    int row = p / CH, c = p - row * CH;
    const float* sr = nullptr;
    if (s) sr = s + (size_t)row * Ksrc + c * 8;
    else if (row < 20)      sr = W21 + (size_t)row * 400 + c * 8;
    else if (row < 40)      sr = W22 + (size_t)(row - 20) * 400 + c * 8;

    short8 v;
    if (c < DC && sr) {
        f4 a = *(const f4*)sr;
        f4 b = *(const f4*)(sr + 4);
#pragma unroll
        for (int e = 0; e < 4; ++e) { v[e] = bf16r(a[e]); v[4 + e] = bf16r(b[e]); }
    } else {
#pragma unroll
        for (int e = 0; e < 8; ++e) v[e] = 0;
    }
    *(short8*)(d + (size_t)row * (CH * 8) + c * 8) = v;
}

// ---------------------------------------------------------------------------
// k_gemm1: h1b = bf16(relu(x @ W1^T + b1))   [4096,416pad]
// BM=64, BN=80, BK=64, 13 steps, double-buffered.
// A (x f32) reg-staged with in-flight conversion; B via global_load_lds.
// LDS chunk swizzle: position (r, c') holds logical chunk c = c' ^ (r&7).
// grid (5, 64), 256 threads (4 waves, wave w owns rows w*16..w*16+15).
// ---------------------------------------------------------------------------
__global__ __launch_bounds__(256)
void k_gemm1(const float* __restrict__ x, const float* __restrict__ b1,
             const short* __restrict__ W1b, short* __restrict__ h1b) {
    __shared__ short sA[2][64 * 64];   // 8KB each
    __shared__ short sB[2][80 * 64];   // 10KB each

    const int tid = threadIdx.x;
    const int w = tid >> 6, l = tid & 63, lg = l >> 4, lr = l & 15;
    const int bn = blockIdx.x, bm = blockIdx.y;
    const int arow = tid >> 2;          // A-load row (2 chunks/thread, same row)
    const int ac0  = (tid & 3) * 2;     // logical chunk pair {ac0, ac0+1}

    f4 acc[5] = {};
    f4 ar[4];

    auto a_load = [&](int kt) {
        const float* base = x + (size_t)(bm * 64 + arow) * DIN + kt * 64;
#pragma unroll
        for (int i = 0; i < 2; ++i) {
            int gk = kt * 64 + (ac0 + i) * 8;
            if (gk < DIN) {
                ar[2 * i]     = *(const f4*)(base + (ac0 + i) * 8);
                ar[2 * i + 1] = *(const f4*)(base + (ac0 + i) * 8 + 4);
            } else {
                ar[2 * i] = (f4){0.f, 0.f, 0.f, 0.f};
                ar[2 * i + 1] = (f4){0.f, 0.f, 0.f, 0.f};
            }
        }
    };
    auto a_write = [&](int buf) {
#pragma unroll
        for (int i = 0; i < 2; ++i) {
            short8 v;
#pragma unroll
            for (int e = 0; e < 4; ++e) { v[e] = bf16r(ar[2 * i][e]); v[4 + e] = bf16r(ar[2 * i + 1][e]); }
            int c = ac0 + i;
            *(short8*)&sA[buf][(arow * 8 + (c ^ (arow & 7))) * 8] = v;
        }
    };
    auto b_stage = [&](int buf, int kt) {   // 640 chunks via glds (linear dest)
#pragma unroll
        for (int it = 0; it < 3; ++it) {
            int p = it * 256 + tid;
            if (p < 640) {
                int r = p >> 3, cp = p & 7, c = cp ^ (r & 7);
                glds16(W1b + (size_t)(bn * 80 + r) * KP1 + kt * 64 + c * 8, &sB[buf][p * 8]);
            }
        }
    };
    auto compute = [&](int buf) {
        const int row = w * 16 + lr;
#pragma unroll
        for (int kk = 0; kk < 2; ++kk) {
            short8 a = *(const short8*)&sA[buf][(row * 8 + ((kk * 4 + lg) ^ (row & 7))) * 8];
#pragma unroll
            for (int ni = 0; ni < 5; ++ni) {
                int br = ni * 16 + lr;
                short8 b = *(const short8*)&sB[buf][(br * 8 + ((kk * 4 + lg) ^ (br & 7))) * 8];
                acc[ni] = __builtin_amdgcn_mfma_f32_16x16x32_bf16(a, b, acc[ni], 0, 0, 0);
            }
        }
    };

    // prologue
    a_load(0); b_stage(0, 0); a_write(0);
    __syncthreads();
    for (int kt = 0; kt < 13; ++kt) {
        const int cur = kt & 1, nxt = kt + 1;
        if (nxt < 13) { a_load(nxt); b_stage(nxt & 1, nxt); }
        compute(cur);
        if (nxt < 13) a_write(nxt & 1);
        __syncthreads();
    }

    // epilogue: bias + relu + bf16 store
#pragma unroll
    for (int ni = 0; ni < 5; ++ni) {
        int col = bn * 80 + ni * 16 + lr;
        float bias = b1[col];
#pragma unroll
        for (int r = 0; r < 4; ++r) {
            int row = bm * 64 + w * 16 + lg * 4 + r;
            float v = acc[ni][r] + bias;
            h1b[(size_t)row * KPH + col] = bf16r(v > 0.f ? v : 0.f);
        }
    }
    if (bn == 4) {   // zero pad cols 400..415
        for (int p = tid; p < 64 * 16; p += 256) {
            int r = p >> 4, c = 400 + (p & 15);
            h1b[(size_t)(bm * 64 + r) * KPH + c] = 0;
        }
    }
}

// ---------------------------------------------------------------------------
// k_gemm2: mu/logvar = h1b @ W2cat^T + bias   (MFMA, single-shot K=416)
// 1 wave/block, BM=16, N=48 (40 real). grid 256 x 64 threads.
// ---------------------------------------------------------------------------
__global__ __launch_bounds__(64)
void k_gemm2(const short* __restrict__ h1b, const short* __restrict__ W2c,
             const float* __restrict__ b21, const float* __restrict__ b22,
             float* __restrict__ out) {
    __shared__ short sA[16 * 416];   // 13312 B
    __shared__ short sB[48 * 416];   // 39936 B
    const int l = threadIdx.x, lg = l >> 4, lr = l & 15;
    const int blk = blockIdx.x;

    for (int it = 0; it < 13; ++it) {           // A: 16*52 = 832 chunks
        int p = it * 64 + l;
        int r = p / 52, cp = p - r * 52, c = cp ^ (r & 3);
        glds16(h1b + (size_t)(blk * 16 + r) * KPH + c * 8, &sA[p * 8]);
    }
    for (int it = 0; it < 39; ++it) {           // B: 48*52 = 2496 chunks
        int p = it * 64 + l;
        int r = p / 52, cp = p - r * 52, c = cp ^ (r & 3);
        glds16(W2c + (size_t)r * KPH + c * 8, &sB[p * 8]);
    }
    __syncthreads();

    f4 acc[3] = {};
#pragma unroll
    for (int kk = 0; kk < 13; ++kk) {
        short8 a = *(const short8*)&sA[(lr * 52 + ((kk * 4 + lg) ^ (lr & 3))) * 8];
#pragma unroll
        for (int ni = 0; ni < 3; ++ni) {
            int br = ni * 16 + lr;
            short8 b = *(const short8*)&sB[(br * 52 + ((kk * 4 + lg) ^ (br & 3))) * 8];
            acc[ni] = __builtin_amdgcn_mfma_f32_16x16x32_bf16(a, b, acc[ni], 0, 0, 0);
        }
    }
#pragma unroll
    for (int ni = 0; ni < 3; ++ni) {
        int n = ni * 16 + lr;
        if (n >= 40) continue;
        float bias = (n < 20) ? b21[n] : b22[n - 20];
        size_t base = (n < 20) ? (size_t)(OFF_MU + n) : (size_t)(OFF_LV + n - 20);
#pragma unroll
        for (int r = 0; r < 4; ++r) {
            int row = blk * 16 + lg * 4 + r;
            out[base + (size_t)row * 20] = acc[ni][r] + bias;
        }
    }
}

// ---------------------------------------------------------------------------
// k_z: z[s][b][j] = mu[b][j] +/- sqrt(20)*lv[b][sp]*(j==sp), f4-vectorized.
// 819200 f4-chunks -> grid 3200 x 256.
// ---------------------------------------------------------------------------
__global__ void k_z(float* __restrict__ out) {
    int idx = blockIdx.x * 256 + threadIdx.x;       // < 819200
    int s = idx / 20480;
    int rem = idx - s * 20480;
    int b = rem / 5, j4 = rem - b * 5;
    int sp = (s < 20) ? s : s - 20;
    float sgn = (s < 20) ? SQRT20F : -SQRT20F;
    f4 v = *(const f4*)(out + OFF_MU + (size_t)b * 20 + j4 * 4);
    if ((sp >> 2) == j4) {
        float add = sgn * out[OFF_LV + (size_t)b * 20 + sp];
        int e = sp & 3;
#pragma unroll
        for (int k = 0; k < 4; ++k) v[k] += (e == k) ? add : 0.f;
    }
    *(f4*)(out + OFF_Z + (size_t)idx * 4) = v;
}

// ---------------------------------------------------------------------------
// k_h3: h3b = bf16(relu(z_last @ W3^T + b3)), [4096][448] zero-padded.
// z_last[j] = mu[j] - (j==19)*sqrt(20)*lv[19]. grid 7168 x 256.
// ---------------------------------------------------------------------------
__global__ void k_h3(const float* __restrict__ out_ro, const float* __restrict__ W3,
                     const float* __restrict__ b3, short* __restrict__ h3b) {
    int gid = blockIdx.x * 256 + threadIdx.x;       // 4096*448
    int b = gid / KPD, n = gid - b * KPD;
    if (n >= DH) { h3b[gid] = 0; return; }
    const float* mu = out_ro + OFF_MU + (size_t)b * 20;
    float lv19 = out_ro[OFF_LV + (size_t)b * 20 + 19];
    const float* wr = W3 + n * DZ;
    float a = b3[n];
#pragma unroll
    for (int j = 0; j < DZ; ++j) a += mu[j] * wr[j];
    a -= SQRT20F * lv19 * wr[19];
    a = a > 0.f ? a : 0.f;
    h3b[gid] = bf16r(a);
}

// ---------------------------------------------------------------------------
// k_gemm4: recon_mu/recon_var = h3b @ W41b^T/W42b^T + bias (dual-B MFMA)
// BM=64, BN=112, BK=32, 14 steps, double-buffered glds. grid (7, 64) x 256.
// ---------------------------------------------------------------------------
__global__ __launch_bounds__(256)
void k_gemm4(const short* __restrict__ h3b, const short* __restrict__ W41b,
             const short* __restrict__ W42b, const float* __restrict__ b41,
             const float* __restrict__ b42, float* __restrict__ out) {
    __shared__ short sA[2][64 * 32];     // 4KB each
    __shared__ short sB1[2][112 * 32];   // 7KB each
    __shared__ short sB2[2][112 * 32];

    const int tid = threadIdx.x;
    const int w = tid >> 6, l = tid & 63, lg = l >> 4, lr = l & 15;
    const int bn = blockIdx.x, bm = blockIdx.y;

    f4 acc[7][2] = {};

    auto stage = [&](int buf, int kt) {
        {   // A: 256 chunks, 1/thread
            int r = tid >> 2, cp = tid & 3, c = cp ^ (r & 3);
            glds16(h3b + (size_t)(bm * 64 + r) * KPD + kt * 32 + c * 8, &sA[buf][tid * 8]);
        }
#pragma unroll
        for (int it = 0; it < 2; ++it) {     // B1/B2: 448 chunks each
            int p = it * 256 + tid;
            if (p < 448) {
                int r = p >> 2, cp = p & 3, c = cp ^ (r & 3);
                size_t go = (size_t)(bn * 112 + r) * KPD + kt * 32 + c * 8;
                glds16(W41b + go, &sB1[buf][p * 8]);
                glds16(W42b + go, &sB2[buf][p * 8]);
            }
        }
    };

    stage(0, 0);
    __syncthreads();
    for (int kt = 0; kt < 14; ++kt) {
        const int cur = kt & 1, nxt = kt + 1;
        if (nxt < 14) stage(nxt & 1, nxt);
        const int arow = w * 16 + lr;
        short8 a = *(const short8*)&sA[cur][(arow * 4 + (lg ^ (arow & 3))) * 8];
#pragma unroll
        for (int ni = 0; ni < 7; ++ni) {
            int br = ni * 16 + lr;
            int ba = (br * 4 + (lg ^ (br & 3))) * 8;
            short8 v1 = *(const short8*)&sB1[cur][ba];
            short8 v2 = *(const short8*)&sB2[cur][ba];
            acc[ni][0] = __builtin_amdgcn_mfma_f32_16x16x32_bf16(a, v1, acc[ni][0], 0, 0, 0);
            acc[ni][1] = __builtin_amdgcn_mfma_f32_16x16x32_bf16(a, v2, acc[ni][1], 0, 0, 0);
        }
        __syncthreads();
    }

#pragma unroll
    for (int ni = 0; ni < 7; ++ni) {
        int col = bn * 112 + ni * 16 + lr;
        float bb1 = b41[col], bb2 = b42[col];
#pragma unroll
        for (int r = 0; r < 4; ++r) {
            size_t row = (size_t)(bm * 64 + w * 16 + lg * 4 + r);
            out[OFF_RMU  + row * DIN + col] = acc[ni][0][r] + bb1;
            out[OFF_RVAR + row * DIN + col] = acc[ni][1][r] + bb2;
        }
    }
}

// ---------------------------------------------------------------------------
extern "C" void kernel_launch(void* const* d_in, const int* in_sizes, int n_in,
                              void* d_out, int out_size, void* d_ws, size_t ws_size,
                              hipStream_t stream) {
    const float* x   = (const float*)d_in[0];
    const float* W1  = (const float*)d_in[1];
    const float* b1  = (const float*)d_in[2];
    const float* W21 = (const float*)d_in[3];
    const float* b21 = (const float*)d_in[4];
    const float* W22 = (const float*)d_in[5];
    const float* b22 = (const float*)d_in[6];
    const float* W3  = (const float*)d_in[7];
    const float* b3  = (const float*)d_in[8];
    const float* W41 = (const float*)d_in[9];
    const float* b41 = (const float*)d_in[10];
    const float* W42 = (const float*)d_in[11];
    const float* b42 = (const float*)d_in[12];

    float* out = (float*)d_out;
    char*  ws  = (char*)d_ws;
    const short* W1b  = (const short*)(ws + WS_W1B);
    const short* W41b = (const short*)(ws + WS_W41B);
    const short* W42b = (const short*)(ws + WS_W42B);
    const short* W2c  = (const short*)(ws + WS_W2C);
    short* h1b = (short*)(ws + WS_H1B);
    short* h3b = (short*)(ws + WS_H3B);

    k_cvt<<<516, 256, 0, stream>>>(W1, W41, W42, W21, W22, ws);
    k_gemm1<<<dim3(5, 64), 256, 0, stream>>>(x, b1, W1b, h1b);
    k_gemm2<<<256, 64, 0, stream>>>(h1b, W2c, b21, b22, out);
    k_z<<<3200, 256, 0, stream>>>(out);
    k_h3<<<7168, 256, 0, stream>>>(out, W3, b3, h3b);
    k_gemm4<<<dim3(7, 64), 256, 0, stream>>>(h3b, W41b, W42b, b41, b42, out);
}

// Round 3
// 49.105 us; speedup vs baseline: 2.8078x; 1.4090x over previous
//
#include <hip/hip_runtime.h>
#include <hip/hip_bf16.h>

// Problem dims
#define BS   4096
#define DIN  784
#define DH   400
#define DZ   20

#define KPH  416    // h1b / W2c row length (400 -> 416)
#define KPD  448    // h3b / Wcat row length (400 -> 448)

// Output layout (f32 elements)
#define OFF_RMU  0
#define OFF_RVAR 3211264
#define OFF_MU   6422528
#define OFF_LV   6504448
#define OFF_Z    6586368

// Workspace layout (bytes)
#define WS_WCAT  0          // bf16 [1568][448] = 1404928 (rows 0..783 W41, 784..1567 W42)
#define WS_W2C   1404928    // bf16 [48][416]   = 39936
#define WS_H1B   1444864    // bf16 [4096][416] = 3407872
#define WS_H3B   4852736    // bf16 [4096][448] = 3670016
// total 8522752 bytes

#define SQRT20F 4.47213595499958f

using short8 = __attribute__((ext_vector_type(8))) short;
using f4     = __attribute__((ext_vector_type(4))) float;

__device__ __forceinline__ short bf16r(float f) {
    union { float f; unsigned u; } v; v.f = f;
    unsigned r = (v.u + 0x7fffu + ((v.u >> 16) & 1u)) >> 16;
    return (short)r;
}

__device__ __forceinline__ void glds16(const void* g, void* l) {
    __builtin_amdgcn_global_load_lds(
        (const __attribute__((address_space(1))) unsigned int*)g,
        (__attribute__((address_space(3))) unsigned int*)l,
        16, 0, 0);
}

// ---------------------------------------------------------------------------
// K1: blocks 0..319: h1b = bf16(relu(x @ W1^T + b1)), BM=64,BN=80,BK=64.
//     A (x) and B (W1) both reg-staged f32->bf16, double-buffered.
//     blocks 320..383: convert W41/W42 -> Wcat[1568][448], W21/W22 -> W2c.
// ---------------------------------------------------------------------------
__global__ __launch_bounds__(256)
void k1(const float* __restrict__ x, const float* __restrict__ W1,
        const float* __restrict__ b1,
        const float* __restrict__ W41, const float* __restrict__ W42,
        const float* __restrict__ W21, const float* __restrict__ W22,
        short* __restrict__ h1b, char* __restrict__ ws) {
    __shared__ short sA[2][64 * 64];   // 8KB each
    __shared__ short sB[2][80 * 64];   // 10KB each

    const int tid = threadIdx.x;
    const int bid = blockIdx.x;

    if (bid >= 320) {
        // ---- weight conversion tail ----
        short* wcat = (short*)(ws + WS_WCAT);
        short* w2c  = (short*)(ws + WS_W2C);
        const int NC = 1568 * 56 + 48 * 52;   // 90304 chunks
        for (int p = (bid - 320) * 256 + tid; p < NC; p += 64 * 256) {
            const float* sr = nullptr;
            short* dst;
            int c;
            if (p < 1568 * 56) {
                int row = p / 56; c = p - row * 56;
                sr = (row < 784) ? (W41 + (size_t)row * DH)
                                 : (W42 + (size_t)(row - 784) * DH);
                dst = wcat + (size_t)row * KPD + c * 8;
            } else {
                int q = p - 1568 * 56;
                int row = q / 52; c = q - row * 52;
                if (row < 20)      sr = W21 + (size_t)row * DH;
                else if (row < 40) sr = W22 + (size_t)(row - 20) * DH;
                dst = w2c + (size_t)row * KPH + c * 8;
            }
            short8 v;
            if (c < 50 && sr) {
                f4 a = *(const f4*)(sr + c * 8);
                f4 b = *(const f4*)(sr + c * 8 + 4);
#pragma unroll
                for (int e = 0; e < 4; ++e) { v[e] = bf16r(a[e]); v[4 + e] = bf16r(b[e]); }
            } else {
#pragma unroll
                for (int e = 0; e < 8; ++e) v[e] = 0;
            }
            *(short8*)dst = v;
        }
        return;
    }

    // ---- gemm1 ----
    const int swz = (bid & 7) * 40 + (bid >> 3);   // XCD-chunked
    const int bm = swz / 5, bn = swz - bm * 5;
    const int w = tid >> 6, l = tid & 63, lg = l >> 4, lr = l & 15;

    f4 acc[5] = {};
    f4 ar[4];     // A: 2 chunks of 8 f32
    f4 br[6];     // B: up to 3 chunks

    auto a_load = [&](int kt) {
#pragma unroll
        for (int i = 0; i < 2; ++i) {
            int c = tid + i * 256;
            int row = c >> 3, kc = c & 7;
            int gk = kt * 64 + kc * 8;
            if (gk < DIN) {
                const float* src = x + (size_t)(bm * 64 + row) * DIN + gk;
                ar[2 * i] = *(const f4*)src;
                ar[2 * i + 1] = *(const f4*)(src + 4);
            } else {
                ar[2 * i] = (f4){0.f, 0.f, 0.f, 0.f};
                ar[2 * i + 1] = (f4){0.f, 0.f, 0.f, 0.f};
            }
        }
    };
    auto b_load = [&](int kt) {
#pragma unroll
        for (int i = 0; i < 3; ++i) {
            int c = tid + i * 256;
            if (c < 640) {
                int row = c >> 3, kc = c & 7;
                int gk = kt * 64 + kc * 8;
                if (gk < DIN) {
                    const float* src = W1 + (size_t)(bn * 80 + row) * DIN + gk;
                    br[2 * i] = *(const f4*)src;
                    br[2 * i + 1] = *(const f4*)(src + 4);
                } else {
                    br[2 * i] = (f4){0.f, 0.f, 0.f, 0.f};
                    br[2 * i + 1] = (f4){0.f, 0.f, 0.f, 0.f};
                }
            }
        }
    };
    auto ab_write = [&](int buf) {
#pragma unroll
        for (int i = 0; i < 2; ++i) {
            int c = tid + i * 256;
            int row = c >> 3, kc = c & 7;
            short8 v;
#pragma unroll
            for (int e = 0; e < 4; ++e) { v[e] = bf16r(ar[2 * i][e]); v[4 + e] = bf16r(ar[2 * i + 1][e]); }
            *(short8*)&sA[buf][(row * 8 + (kc ^ (row & 7))) * 8] = v;
        }
#pragma unroll
        for (int i = 0; i < 3; ++i) {
            int c = tid + i * 256;
            if (c < 640) {
                int row = c >> 3, kc = c & 7;
                short8 v;
#pragma unroll
                for (int e = 0; e < 4; ++e) { v[e] = bf16r(br[2 * i][e]); v[4 + e] = bf16r(br[2 * i + 1][e]); }
                *(short8*)&sB[buf][(row * 8 + (kc ^ (row & 7))) * 8] = v;
            }
        }
    };
    auto compute = [&](int buf) {
        const int row = w * 16 + lr;
#pragma unroll
        for (int kk = 0; kk < 2; ++kk) {
            short8 a = *(const short8*)&sA[buf][(row * 8 + ((kk * 4 + lg) ^ (row & 7))) * 8];
#pragma unroll
            for (int ni = 0; ni < 5; ++ni) {
                int brw = ni * 16 + lr;
                short8 b = *(const short8*)&sB[buf][(brw * 8 + ((kk * 4 + lg) ^ (brw & 7))) * 8];
                acc[ni] = __builtin_amdgcn_mfma_f32_16x16x32_bf16(a, b, acc[ni], 0, 0, 0);
            }
        }
    };

    a_load(0); b_load(0); ab_write(0);
    __syncthreads();
    for (int kt = 0; kt < 13; ++kt) {
        const int cur = kt & 1;
        if (kt < 12) { a_load(kt + 1); b_load(kt + 1); }
        compute(cur);
        if (kt < 12) ab_write(cur ^ 1);
        __syncthreads();
    }

#pragma unroll
    for (int ni = 0; ni < 5; ++ni) {
        int col = bn * 80 + ni * 16 + lr;
        float bias = b1[col];
#pragma unroll
        for (int r = 0; r < 4; ++r) {
            int row = bm * 64 + w * 16 + lg * 4 + r;
            float v = acc[ni][r] + bias;
            h1b[(size_t)row * KPH + col] = bf16r(v > 0.f ? v : 0.f);
        }
    }
    if (bn == 4) {   // zero-pad h1b cols 400..415
        for (int p = tid; p < 64 * 16; p += 256) {
            int r = p >> 4, c = 400 + (p & 15);
            h1b[(size_t)(bm * 64 + r) * KPH + c] = 0;
        }
    }
}

// ---------------------------------------------------------------------------
// K2 (mid): per block 16 batch rows:
//   mu/lv = h1b @ W2c^T (MFMA, wave0) -> out + LDS
//   z writes (all 40 sigma points)
//   h3 = relu(z_last @ W3^T + b3) via MFMA -> h3b (coalesced via LDS buffer)
// grid 256 x 256.
// ---------------------------------------------------------------------------
__global__ __launch_bounds__(256)
void k_mid(const short* __restrict__ h1b, const short* __restrict__ w2c,
           const float* __restrict__ W3, const float* __restrict__ b3,
           const float* __restrict__ b21, const float* __restrict__ b22,
           float* __restrict__ out, short* __restrict__ h3b) {
    __shared__ short sA[16 * 416];     // 13312 B
    __shared__ short sB[48 * 416];     // 39936 B
    __shared__ short sW[400 * 40];     // 32000 B (W3 bf16, K pad 32, row pad 40)
    __shared__ float muv[2][16][20];   // mu, lv
    __shared__ short zl[16 * 40];      // z_last bf16, K pad 32, row pad 40
    __shared__ short h3s[16 * 448];    // h3 staging for coalesced store

    const int tid = threadIdx.x;
    const int blk = blockIdx.x;
    const int w = tid >> 6, l = tid & 63, lg = l >> 4, lr = l & 15;
    const int r0 = blk * 16;

    // stage A (16 h1b rows) + B (W2c) via glds, chunk-swizzled source
#pragma unroll
    for (int it = 0; it < 4; ++it) {
        int p = it * 256 + tid;
        if (p < 832) {
            int r = p / 52, cp = p - r * 52, c = cp ^ (r & 3);
            glds16(h1b + (size_t)(r0 + r) * KPH + c * 8, &sA[p * 8]);
        }
    }
#pragma unroll
    for (int it = 0; it < 10; ++it) {
        int p = it * 256 + tid;
        if (p < 2496) {
            int r = p / 52, cp = p - r * 52, c = cp ^ (r & 3);
            glds16(w2c + (size_t)r * KPH + c * 8, &sB[p * 8]);
        }
    }
    // stage W3 -> bf16 padded [400][40] (cols 20..31 zero)
    if (tid < 200) {
#pragma unroll
        for (int i = 0; i < 2; ++i) {
            int r = tid + i * 200;
            const float* src = W3 + (size_t)r * DZ;
            f4 f0 = *(const f4*)src;
            f4 f1 = *(const f4*)(src + 4);
            f4 f2 = *(const f4*)(src + 8);
            f4 f3 = *(const f4*)(src + 12);
            f4 f5 = *(const f4*)(src + 16);
            short8 c0, c1, c2, c3;
#pragma unroll
            for (int e = 0; e < 4; ++e) {
                c0[e] = bf16r(f0[e]); c0[4 + e] = bf16r(f1[e]);
                c1[e] = bf16r(f2[e]); c1[4 + e] = bf16r(f3[e]);
                c2[e] = bf16r(f5[e]); c2[4 + e] = 0;
                c3[e] = 0; c3[4 + e] = 0;
            }
            *(short8*)&sW[r * 40 + 0]  = c0;
            *(short8*)&sW[r * 40 + 8]  = c1;
            *(short8*)&sW[r * 40 + 16] = c2;
            *(short8*)&sW[r * 40 + 24] = c3;
        }
    }
    __syncthreads();

    // phase 1: mu/lv MFMA (wave 0 only)
    if (w == 0) {
        f4 a3[3] = {};
#pragma unroll
        for (int kk = 0; kk < 13; ++kk) {
            short8 a = *(const short8*)&sA[(lr * 52 + ((kk * 4 + lg) ^ (lr & 3))) * 8];
#pragma unroll
            for (int ni = 0; ni < 3; ++ni) {
                int br = ni * 16 + lr;
                short8 b = *(const short8*)&sB[(br * 52 + ((kk * 4 + lg) ^ (br & 3))) * 8];
                a3[ni] = __builtin_amdgcn_mfma_f32_16x16x32_bf16(a, b, a3[ni], 0, 0, 0);
            }
        }
#pragma unroll
        for (int ni = 0; ni < 3; ++ni) {
            int n = ni * 16 + lr;
            if (n < 40) {
                float bias = (n < 20) ? b21[n] : b22[n - 20];
#pragma unroll
                for (int r = 0; r < 4; ++r) {
                    int row = lg * 4 + r;
                    float v = a3[ni][r] + bias;
                    if (n < 20) {
                        muv[0][row][n] = v;
                        out[OFF_MU + (size_t)(r0 + row) * 20 + n] = v;
                    } else {
                        muv[1][row][n - 20] = v;
                        out[OFF_LV + (size_t)(r0 + row) * 20 + (n - 20)] = v;
                    }
                }
            }
        }
    }
    __syncthreads();

    // phase 2: build z_last bf16, zero h3s pad cols, write z
    if (tid < 80) {
        int row = tid / 5, c = tid - (tid / 5) * 5;
        short8 v;
#pragma unroll
        for (int e = 0; e < 8; ++e) {
            int j = c * 8 + e;
            float val = 0.f;
            if (j < 20) {
                val = muv[0][row][j];
                if (j == 19) val -= SQRT20F * muv[1][row][19];
            }
            v[e] = bf16r(val);
        }
        *(short8*)&zl[row * 40 + c * 8] = v;
    } else if (tid < 176) {
        int t = tid - 80;           // 96 chunks: h3s cols 400..447
        int row = t / 6, c = t - (t / 6) * 6;
        short8 zz;
#pragma unroll
        for (int e = 0; e < 8; ++e) zz[e] = 0;
        *(short8*)&h3s[row * 448 + 400 + c * 8] = zz;
    }
#pragma unroll
    for (int it = 0; it < 13; ++it) {
        int p = it * 256 + tid;
        if (p < 3200) {
            int s = p / 80, q = p - s * 80;
            int row = q / 5, j4 = q - (q / 5) * 5;
            f4 v = *(const f4*)&muv[0][row][j4 * 4];
            int sp = (s < 20) ? s : s - 20;
            if ((sp >> 2) == j4) {
                float add = ((s < 20) ? SQRT20F : -SQRT20F) * muv[1][row][sp];
                int e = sp & 3;
#pragma unroll
                for (int k = 0; k < 4; ++k) v[k] += (e == k) ? add : 0.f;
            }
            *(f4*)(out + OFF_Z + ((size_t)s * BS + r0 + row) * 20 + j4 * 4) = v;
        }
    }
    __syncthreads();

    // phase 3: h3 MFMA (all waves, frags strided by 4) -> h3s
    for (int f = w; f < 25; f += 4) {
        int n0 = f * 16;
        short8 a = *(const short8*)&zl[lr * 40 + lg * 8];
        short8 b = *(const short8*)&sW[(n0 + lr) * 40 + lg * 8];
        f4 z4 = {};
        f4 accv = __builtin_amdgcn_mfma_f32_16x16x32_bf16(a, b, z4, 0, 0, 0);
        int n = n0 + lr;
        float bias = b3[n];
#pragma unroll
        for (int r = 0; r < 4; ++r) {
            int row = lg * 4 + r;
            float v = accv[r] + bias;
            h3s[row * 448 + n] = bf16r(v > 0.f ? v : 0.f);
        }
    }
    __syncthreads();

    // phase 4: coalesced h3b dump
#pragma unroll
    for (int it = 0; it < 4; ++it) {
        int p = it * 256 + tid;
        if (p < 896) {
            int row = p / 56, c = p - (p / 56) * 56;
            *(short8*)(h3b + (size_t)(r0 + row) * KPD + c * 8) =
                *(const short8*)&h3s[row * 448 + c * 8];
        }
    }
}

// ---------------------------------------------------------------------------
// K3: [recon_mu | recon_var] = h3b @ Wcat^T + bias
// M=4096, N=1568, K=448. BM=64, BN=112, BK=64, dbuf glds. grid 896.
// ---------------------------------------------------------------------------
__global__ __launch_bounds__(256)
void k_gemm4(const short* __restrict__ h3b, const short* __restrict__ wcat,
             const float* __restrict__ b41, const float* __restrict__ b42,
             float* __restrict__ out) {
    __shared__ short sA[2][64 * 64];    // 8KB each
    __shared__ short sB[2][112 * 64];   // 14KB each

    const int tid = threadIdx.x;
    const int bid = blockIdx.x;
    const int swz = (bid & 7) * 112 + (bid >> 3);   // XCD-chunked
    const int bm = swz / 14, bn = swz - bm * 14;
    const int w = tid >> 6, l = tid & 63, lg = l >> 4, lr = l & 15;

    f4 acc[7] = {};

    auto stage = [&](int buf, int kt) {
#pragma unroll
        for (int i = 0; i < 2; ++i) {              // A: 512 chunks
            int c = tid + i * 256;
            int r = c >> 3, kc = (c & 7) ^ (r & 7);
            glds16(h3b + (size_t)(bm * 64 + r) * KPD + kt * 64 + kc * 8, &sA[buf][c * 8]);
        }
#pragma unroll
        for (int i = 0; i < 4; ++i) {              // B: 896 chunks
            int c = tid + i * 256;
            if (c < 896) {
                int r = c >> 3, kc = (c & 7) ^ (r & 7);
                glds16(wcat + (size_t)(bn * 112 + r) * KPD + kt * 64 + kc * 8, &sB[buf][c * 8]);
            }
        }
    };

    stage(0, 0);
    __syncthreads();
    for (int kt = 0; kt < 7; ++kt) {
        const int cur = kt & 1;
        if (kt < 6) stage(cur ^ 1, kt + 1);
        const int arow = w * 16 + lr;
#pragma unroll
        for (int kk = 0; kk < 2; ++kk) {
            short8 a = *(const short8*)&sA[cur][(arow * 8 + ((kk * 4 + lg) ^ (arow & 7))) * 8];
#pragma unroll
            for (int ni = 0; ni < 7; ++ni) {
                int br = ni * 16 + lr;
                short8 b = *(const short8*)&sB[cur][(br * 8 + ((kk * 4 + lg) ^ (br & 7))) * 8];
                acc[ni] = __builtin_amdgcn_mfma_f32_16x16x32_bf16(a, b, acc[ni], 0, 0, 0);
            }
        }
        __syncthreads();
    }

    const bool first = (bn < 7);
#pragma unroll
    for (int ni = 0; ni < 7; ++ni) {
        int colt = bn * 112 + ni * 16 + lr;
        int cc = first ? colt : colt - 784;
        float bias = first ? b41[cc] : b42[cc];
        size_t base = first ? (size_t)OFF_RMU : (size_t)OFF_RVAR;
#pragma unroll
        for (int r = 0; r < 4; ++r) {
            size_t row = (size_t)(bm * 64 + w * 16 + lg * 4 + r);
            out[base + row * DIN + cc] = acc[ni][r] + bias;
        }
    }
}

// ---------------------------------------------------------------------------
extern "C" void kernel_launch(void* const* d_in, const int* in_sizes, int n_in,
                              void* d_out, int out_size, void* d_ws, size_t ws_size,
                              hipStream_t stream) {
    const float* x   = (const float*)d_in[0];
    const float* W1  = (const float*)d_in[1];
    const float* b1  = (const float*)d_in[2];
    const float* W21 = (const float*)d_in[3];
    const float* b21 = (const float*)d_in[4];
    const float* W22 = (const float*)d_in[5];
    const float* b22 = (const float*)d_in[6];
    const float* W3  = (const float*)d_in[7];
    const float* b3  = (const float*)d_in[8];
    const float* W41 = (const float*)d_in[9];
    const float* b41 = (const float*)d_in[10];
    const float* W42 = (const float*)d_in[11];
    const float* b42 = (const float*)d_in[12];

    float* out = (float*)d_out;
    char*  ws  = (char*)d_ws;
    const short* wcat = (const short*)(ws + WS_WCAT);
    const short* w2c  = (const short*)(ws + WS_W2C);
    short* h1b = (short*)(ws + WS_H1B);
    short* h3b = (short*)(ws + WS_H3B);

    k1<<<384, 256, 0, stream>>>(x, W1, b1, W41, W42, W21, W22, h1b, ws);
    k_mid<<<256, 256, 0, stream>>>(h1b, w2c, W3, b3, b21, b22, out, h3b);
    k_gemm4<<<896, 256, 0, stream>>>(h3b, wcat, b41, b42, out);
}

// Round 4
// 44.984 us; speedup vs baseline: 3.0651x; 1.0916x over previous
//
#include <hip/hip_runtime.h>
#include <hip/hip_bf16.h>

// Problem dims
#define BS   4096
#define DIN  784
#define DH   400
#define DZ   20

#define KP1  832    // W1b row length (784 -> 832 = 13*64)
#define KPH  416    // h1b / W2c row length (400 -> 416)
#define KPD  448    // h3b / Wcat row length (400 -> 448)

// Output layout (f32 elements)
#define OFF_RMU  0
#define OFF_RVAR 3211264
#define OFF_MU   6422528
#define OFF_LV   6504448
#define OFF_Z    6586368

// Workspace layout (bytes)
#define WS_WCAT  0          // bf16 [1568][448] = 1404928 (rows 0..783 W41, 784.. W42)
#define WS_W2C   1404928    // bf16 [48][416]   = 39936
#define WS_W1B   1444864    // bf16 [400][832]  = 665600
#define WS_H1B   2110464    // bf16 [4096][416] = 3407872
#define WS_H3B   5518336    // bf16 [4096][448] = 3670016
// total 9188352 bytes

#define SQRT20F 4.47213595499958f

using short8 = __attribute__((ext_vector_type(8))) short;
using f4     = __attribute__((ext_vector_type(4))) float;
using i4     = __attribute__((ext_vector_type(4))) int;

__device__ __forceinline__ short bf16r(float f) {
    union { float f; unsigned u; } v; v.f = f;
    unsigned r = (v.u + 0x7fffu + ((v.u >> 16) & 1u)) >> 16;
    return (short)r;
}

__device__ __forceinline__ void glds16(const void* g, void* l) {
    __builtin_amdgcn_global_load_lds(
        (const __attribute__((address_space(1))) unsigned int*)g,
        (__attribute__((address_space(3))) unsigned int*)l,
        16, 0, 0);
}

// ---------------------------------------------------------------------------
// k0: one-time weight conversion f32 -> bf16 (RTNE), zero K-padding.
// W1 -> W1b[400][832]; W41/W42 -> Wcat[1568][448]; W21/W22 -> W2c[48][416].
// 131904 chunks of 8 elems, 1/thread, grid 516.
// ---------------------------------------------------------------------------
__global__ void k0(const float* __restrict__ W1, const float* __restrict__ W41,
                   const float* __restrict__ W42, const float* __restrict__ W21,
                   const float* __restrict__ W22, char* __restrict__ ws) {
    const int N0 = 400 * 104;                 // W1b
    const int N1 = N0 + 1568 * 56;            // Wcat
    const int N2 = N1 + 48 * 52;              // W2c
    int gid = blockIdx.x * 256 + threadIdx.x;
    if (gid >= N2) return;

    const float* sr = nullptr;
    short* dst;
    int c, DC;
    if (gid < N0) {
        int row = gid / 104; c = gid - row * 104; DC = 98;
        sr = W1 + (size_t)row * DIN;
        dst = (short*)(ws + WS_W1B) + (size_t)row * KP1 + c * 8;
    } else if (gid < N1) {
        int p = gid - N0;
        int row = p / 56; c = p - row * 56; DC = 50;
        sr = (row < 784) ? (W41 + (size_t)row * DH) : (W42 + (size_t)(row - 784) * DH);
        dst = (short*)(ws + WS_WCAT) + (size_t)row * KPD + c * 8;
    } else {
        int p = gid - N1;
        int row = p / 52; c = p - row * 52; DC = 50;
        if (row < 20)      sr = W21 + (size_t)row * DH;
        else if (row < 40) sr = W22 + (size_t)(row - 20) * DH;
        else               sr = nullptr;
        dst = (short*)(ws + WS_W2C) + (size_t)row * KPH + c * 8;
    }
    short8 v;
    if (c < DC && sr) {
        f4 a = *(const f4*)(sr + c * 8);
        f4 b = *(const f4*)(sr + c * 8 + 4);
#pragma unroll
        for (int e = 0; e < 4; ++e) { v[e] = bf16r(a[e]); v[4 + e] = bf16r(b[e]); }
    } else {
#pragma unroll
        for (int e = 0; e < 8; ++e) v[e] = 0;
    }
    *(short8*)dst = v;
}

// ---------------------------------------------------------------------------
// k1: h1b = bf16(relu(x @ W1^T + b1)). BM=64, BN=80, BK=64, 13 steps, dbuf.
// A (x f32) reg-staged with bit-truncation; B (W1b) via global_load_lds.
// grid 320 (XCD-swizzled), 256 threads.
// ---------------------------------------------------------------------------
__global__ __launch_bounds__(256)
void k1(const float* __restrict__ x, const float* __restrict__ b1,
        const short* __restrict__ W1b, short* __restrict__ h1b) {
    __shared__ short sA[2][64 * 64];   // 8KB each
    __shared__ short sB[2][80 * 64];   // 10KB each

    const int tid = threadIdx.x;
    const int bid = blockIdx.x;
    const int swz = (bid & 7) * 40 + (bid >> 3);
    const int bm = swz / 5, bn = swz - bm * 5;
    const int w = tid >> 6, l = tid & 63, lg = l >> 4, lr = l & 15;

    f4 acc[5] = {};
    i4 ar[4];

    auto a_load = [&](int kt) {
#pragma unroll
        for (int i = 0; i < 2; ++i) {
            int c = tid + i * 256;
            int row = c >> 3, kc = c & 7;
            int gk = kt * 64 + kc * 8;
            if (gk < DIN) {
                const int* src = (const int*)(x + (size_t)(bm * 64 + row) * DIN + gk);
                ar[2 * i] = *(const i4*)src;
                ar[2 * i + 1] = *(const i4*)(src + 4);
            } else {
                ar[2 * i] = (i4){0, 0, 0, 0};
                ar[2 * i + 1] = (i4){0, 0, 0, 0};
            }
        }
    };
    auto a_write = [&](int buf) {
#pragma unroll
        for (int i = 0; i < 2; ++i) {
            int c = tid + i * 256;
            int row = c >> 3, kc = c & 7;
            short8 v;
#pragma unroll
            for (int e = 0; e < 4; ++e) {
                v[e]     = (short)(((unsigned)ar[2 * i][e]) >> 16);
                v[4 + e] = (short)(((unsigned)ar[2 * i + 1][e]) >> 16);
            }
            *(short8*)&sA[buf][(row * 8 + (kc ^ (row & 7))) * 8] = v;
        }
    };
    auto b_stage = [&](int buf, int kt) {
#pragma unroll
        for (int it = 0; it < 3; ++it) {
            int p = it * 256 + tid;
            if (p < 640) {
                int r = p >> 3, kc = (p & 7) ^ (r & 7);
                glds16(W1b + (size_t)(bn * 80 + r) * KP1 + kt * 64 + kc * 8, &sB[buf][p * 8]);
            }
        }
    };
    auto compute = [&](int buf) {
        const int row = w * 16 + lr;
#pragma unroll
        for (int kk = 0; kk < 2; ++kk) {
            short8 a = *(const short8*)&sA[buf][(row * 8 + ((kk * 4 + lg) ^ (row & 7))) * 8];
#pragma unroll
            for (int ni = 0; ni < 5; ++ni) {
                int brw = ni * 16 + lr;
                short8 b = *(const short8*)&sB[buf][(brw * 8 + ((kk * 4 + lg) ^ (brw & 7))) * 8];
                acc[ni] = __builtin_amdgcn_mfma_f32_16x16x32_bf16(a, b, acc[ni], 0, 0, 0);
            }
        }
    };

    a_load(0); b_stage(0, 0); a_write(0);
    __syncthreads();
    for (int kt = 0; kt < 13; ++kt) {
        const int cur = kt & 1;
        if (kt < 12) { a_load(kt + 1); b_stage(cur ^ 1, kt + 1); }
        compute(cur);
        if (kt < 12) a_write(cur ^ 1);
        __syncthreads();
    }

#pragma unroll
    for (int ni = 0; ni < 5; ++ni) {
        int col = bn * 80 + ni * 16 + lr;
        float bias = b1[col];
#pragma unroll
        for (int r = 0; r < 4; ++r) {
            int row = bm * 64 + w * 16 + lg * 4 + r;
            float v = acc[ni][r] + bias;
            h1b[(size_t)row * KPH + col] = bf16r(v > 0.f ? v : 0.f);
        }
    }
    if (bn == 4) {
        for (int p = tid; p < 64 * 16; p += 256) {
            int r = p >> 4, c = 400 + (p & 15);
            h1b[(size_t)(bm * 64 + r) * KPH + c] = 0;
        }
    }
}

// ---------------------------------------------------------------------------
// K2 (mid): per block 16 batch rows: mu/lv MFMA -> out+LDS; z writes; h3 MFMA
// -> h3b (coalesced via LDS). grid 256 x 256.
// ---------------------------------------------------------------------------
__global__ __launch_bounds__(256)
void k_mid(const short* __restrict__ h1b, const short* __restrict__ w2c,
           const float* __restrict__ W3, const float* __restrict__ b3,
           const float* __restrict__ b21, const float* __restrict__ b22,
           float* __restrict__ out, short* __restrict__ h3b) {
    __shared__ short sA[16 * 416];
    __shared__ short sB[48 * 416];
    __shared__ short sW[400 * 40];
    __shared__ float muv[2][16][20];
    __shared__ short zl[16 * 40];
    __shared__ short h3s[16 * 448];

    const int tid = threadIdx.x;
    const int blk = blockIdx.x;
    const int w = tid >> 6, l = tid & 63, lg = l >> 4, lr = l & 15;
    const int r0 = blk * 16;

#pragma unroll
    for (int it = 0; it < 4; ++it) {
        int p = it * 256 + tid;
        if (p < 832) {
            int r = p / 52, cp = p - r * 52, c = cp ^ (r & 3);
            glds16(h1b + (size_t)(r0 + r) * KPH + c * 8, &sA[p * 8]);
        }
    }
#pragma unroll
    for (int it = 0; it < 10; ++it) {
        int p = it * 256 + tid;
        if (p < 2496) {
            int r = p / 52, cp = p - r * 52, c = cp ^ (r & 3);
            glds16(w2c + (size_t)r * KPH + c * 8, &sB[p * 8]);
        }
    }
    if (tid < 200) {
#pragma unroll
        for (int i = 0; i < 2; ++i) {
            int r = tid + i * 200;
            const float* src = W3 + (size_t)r * DZ;
            f4 f0 = *(const f4*)src;
            f4 f1 = *(const f4*)(src + 4);
            f4 f2 = *(const f4*)(src + 8);
            f4 f3 = *(const f4*)(src + 12);
            f4 f5 = *(const f4*)(src + 16);
            short8 c0, c1, c2, c3;
#pragma unroll
            for (int e = 0; e < 4; ++e) {
                c0[e] = bf16r(f0[e]); c0[4 + e] = bf16r(f1[e]);
                c1[e] = bf16r(f2[e]); c1[4 + e] = bf16r(f3[e]);
                c2[e] = bf16r(f5[e]); c2[4 + e] = 0;
                c3[e] = 0; c3[4 + e] = 0;
            }
            *(short8*)&sW[r * 40 + 0]  = c0;
            *(short8*)&sW[r * 40 + 8]  = c1;
            *(short8*)&sW[r * 40 + 16] = c2;
            *(short8*)&sW[r * 40 + 24] = c3;
        }
    }
    __syncthreads();

    if (w == 0) {
        f4 a3[3] = {};
#pragma unroll
        for (int kk = 0; kk < 13; ++kk) {
            short8 a = *(const short8*)&sA[(lr * 52 + ((kk * 4 + lg) ^ (lr & 3))) * 8];
#pragma unroll
            for (int ni = 0; ni < 3; ++ni) {
                int br = ni * 16 + lr;
                short8 b = *(const short8*)&sB[(br * 52 + ((kk * 4 + lg) ^ (br & 3))) * 8];
                a3[ni] = __builtin_amdgcn_mfma_f32_16x16x32_bf16(a, b, a3[ni], 0, 0, 0);
            }
        }
#pragma unroll
        for (int ni = 0; ni < 3; ++ni) {
            int n = ni * 16 + lr;
            if (n < 40) {
                float bias = (n < 20) ? b21[n] : b22[n - 20];
#pragma unroll
                for (int r = 0; r < 4; ++r) {
                    int row = lg * 4 + r;
                    float v = a3[ni][r] + bias;
                    if (n < 20) {
                        muv[0][row][n] = v;
                        out[OFF_MU + (size_t)(r0 + row) * 20 + n] = v;
                    } else {
                        muv[1][row][n - 20] = v;
                        out[OFF_LV + (size_t)(r0 + row) * 20 + (n - 20)] = v;
                    }
                }
            }
        }
    }
    __syncthreads();

    if (tid < 80) {
        int row = tid / 5, c = tid - (tid / 5) * 5;
        short8 v;
#pragma unroll
        for (int e = 0; e < 8; ++e) {
            int j = c * 8 + e;
            float val = 0.f;
            if (j < 20) {
                val = muv[0][row][j];
                if (j == 19) val -= SQRT20F * muv[1][row][19];
            }
            v[e] = bf16r(val);
        }
        *(short8*)&zl[row * 40 + c * 8] = v;
    } else if (tid < 176) {
        int t = tid - 80;
        int row = t / 6, c = t - (t / 6) * 6;
        short8 zz;
#pragma unroll
        for (int e = 0; e < 8; ++e) zz[e] = 0;
        *(short8*)&h3s[row * 448 + 400 + c * 8] = zz;
    }
#pragma unroll
    for (int it = 0; it < 13; ++it) {
        int p = it * 256 + tid;
        if (p < 3200) {
            int s = p / 80, q = p - s * 80;
            int row = q / 5, j4 = q - (q / 5) * 5;
            f4 v = *(const f4*)&muv[0][row][j4 * 4];
            int sp = (s < 20) ? s : s - 20;
            if ((sp >> 2) == j4) {
                float add = ((s < 20) ? SQRT20F : -SQRT20F) * muv[1][row][sp];
                int e = sp & 3;
#pragma unroll
                for (int k = 0; k < 4; ++k) v[k] += (e == k) ? add : 0.f;
            }
            *(f4*)(out + OFF_Z + ((size_t)s * BS + r0 + row) * 20 + j4 * 4) = v;
        }
    }
    __syncthreads();

    for (int f = w; f < 25; f += 4) {
        int n0 = f * 16;
        short8 a = *(const short8*)&zl[lr * 40 + lg * 8];
        short8 b = *(const short8*)&sW[(n0 + lr) * 40 + lg * 8];
        f4 z4 = {};
        f4 accv = __builtin_amdgcn_mfma_f32_16x16x32_bf16(a, b, z4, 0, 0, 0);
        int n = n0 + lr;
        float bias = b3[n];
#pragma unroll
        for (int r = 0; r < 4; ++r) {
            int row = lg * 4 + r;
            float v = accv[r] + bias;
            h3s[row * 448 + n] = bf16r(v > 0.f ? v : 0.f);
        }
    }
    __syncthreads();

#pragma unroll
    for (int it = 0; it < 4; ++it) {
        int p = it * 256 + tid;
        if (p < 896) {
            int row = p / 56, c = p - (p / 56) * 56;
            *(short8*)(h3b + (size_t)(r0 + row) * KPD + c * 8) =
                *(const short8*)&h3s[row * 448 + c * 8];
        }
    }
}

// ---------------------------------------------------------------------------
// K3: [recon_mu | recon_var] = h3b @ Wcat^T + bias
// M=4096, N=1568, K=448. BM=128, BN=112, BK=64, dbuf glds. grid 448.
// per-wave 32x112 -> 28 MFMA : 18 ds_read per K-step.
// ---------------------------------------------------------------------------
__global__ __launch_bounds__(256)
void k_gemm4(const short* __restrict__ h3b, const short* __restrict__ wcat,
             const float* __restrict__ b41, const float* __restrict__ b42,
             float* __restrict__ out) {
    __shared__ short sA[2][128 * 64];   // 16KB each
    __shared__ short sB[2][112 * 64];   // 14KB each

    const int tid = threadIdx.x;
    const int bid = blockIdx.x;
    const int swz = (bid & 7) * 56 + (bid >> 3);   // XCD-chunked
    const int bm = swz / 14, bn = swz - bm * 14;
    const int w = tid >> 6, l = tid & 63, lg = l >> 4, lr = l & 15;

    f4 acc[2][7] = {};

    auto stage = [&](int buf, int kt) {
#pragma unroll
        for (int i = 0; i < 4; ++i) {              // A: 1024 chunks
            int c = tid + i * 256;
            int r = c >> 3, kc = (c & 7) ^ (r & 7);
            glds16(h3b + (size_t)(bm * 128 + r) * KPD + kt * 64 + kc * 8, &sA[buf][c * 8]);
        }
#pragma unroll
        for (int i = 0; i < 4; ++i) {              // B: 896 chunks
            int c = tid + i * 256;
            if (c < 896) {
                int r = c >> 3, kc = (c & 7) ^ (r & 7);
                glds16(wcat + (size_t)(bn * 112 + r) * KPD + kt * 64 + kc * 8, &sB[buf][c * 8]);
            }
        }
    };

    stage(0, 0);
    __syncthreads();
    for (int kt = 0; kt < 7; ++kt) {
        const int cur = kt & 1;
        if (kt < 6) stage(cur ^ 1, kt + 1);
        const int row0 = w * 32 + lr, row1 = w * 32 + 16 + lr;
#pragma unroll
        for (int kk = 0; kk < 2; ++kk) {
            short8 a0 = *(const short8*)&sA[cur][(row0 * 8 + ((kk * 4 + lg) ^ (row0 & 7))) * 8];
            short8 a1 = *(const short8*)&sA[cur][(row1 * 8 + ((kk * 4 + lg) ^ (row1 & 7))) * 8];
#pragma unroll
            for (int ni = 0; ni < 7; ++ni) {
                int br = ni * 16 + lr;
                short8 b = *(const short8*)&sB[cur][(br * 8 + ((kk * 4 + lg) ^ (br & 7))) * 8];
                acc[0][ni] = __builtin_amdgcn_mfma_f32_16x16x32_bf16(a0, b, acc[0][ni], 0, 0, 0);
                acc[1][ni] = __builtin_amdgcn_mfma_f32_16x16x32_bf16(a1, b, acc[1][ni], 0, 0, 0);
            }
        }
        __syncthreads();
    }

    const bool first = (bn < 7);
#pragma unroll
    for (int mi = 0; mi < 2; ++mi)
#pragma unroll
        for (int ni = 0; ni < 7; ++ni) {
            int colt = bn * 112 + ni * 16 + lr;
            int cc = first ? colt : colt - 784;
            float bias = first ? b41[cc] : b42[cc];
            size_t base = first ? (size_t)OFF_RMU : (size_t)OFF_RVAR;
#pragma unroll
            for (int r = 0; r < 4; ++r) {
                size_t row = (size_t)(bm * 128 + w * 32 + mi * 16 + lg * 4 + r);
                out[base + row * DIN + cc] = acc[mi][ni][r] + bias;
            }
        }
}

// ---------------------------------------------------------------------------
extern "C" void kernel_launch(void* const* d_in, const int* in_sizes, int n_in,
                              void* d_out, int out_size, void* d_ws, size_t ws_size,
                              hipStream_t stream) {
    const float* x   = (const float*)d_in[0];
    const float* W1  = (const float*)d_in[1];
    const float* b1  = (const float*)d_in[2];
    const float* W21 = (const float*)d_in[3];
    const float* b21 = (const float*)d_in[4];
    const float* W22 = (const float*)d_in[5];
    const float* b22 = (const float*)d_in[6];
    const float* W3  = (const float*)d_in[7];
    const float* b3  = (const float*)d_in[8];
    const float* W41 = (const float*)d_in[9];
    const float* b41 = (const float*)d_in[10];
    const float* W42 = (const float*)d_in[11];
    const float* b42 = (const float*)d_in[12];

    float* out = (float*)d_out;
    char*  ws  = (char*)d_ws;
    const short* wcat = (const short*)(ws + WS_WCAT);
    const short* w2c  = (const short*)(ws + WS_W2C);
    const short* W1b  = (const short*)(ws + WS_W1B);
    short* h1b = (short*)(ws + WS_H1B);
    short* h3b = (short*)(ws + WS_H3B);

    k0<<<516, 256, 0, stream>>>(W1, W41, W42, W21, W22, ws);
    k1<<<320, 256, 0, stream>>>(x, b1, W1b, h1b);
    k_mid<<<256, 256, 0, stream>>>(h1b, w2c, W3, b3, b21, b22, out, h3b);
    k_gemm4<<<448, 256, 0, stream>>>(h3b, wcat, b41, b42, out);
}